// Round 1
// baseline (107.207 us; speedup 1.0000x reference)
//
#include <hip/hip_runtime.h>

// LocallyConnected2d: out[b,o,y,x] = sum_{c,i,j} x[b,c,y+i,x+j] * w[o,c,y,x,i*3+j]
// B=16, C_IN=16, H=W=64, C_OUT=16, KH=KW=3, OH=OW=62.
//
// Memory-bound: weight (35.4 MB fp32) read once; x (4 MB) re-read from L2.
// Thread layout: block 256 = (xc=16 fastest, b=16). Each thread accumulates
// To=8 output channels for one (b, y, xpos). Weight addresses are b-invariant
// -> 16-way same-address merge in-block keeps weight HBM traffic at 1x.

#define CIN   16
#define COUT  16
#define H_    64
#define W_    64
#define OH_   62
#define OW_   62
#define NB    16
#define TO    8

__global__ __launch_bounds__(256, 2)
void lc2d_kernel(const float* __restrict__ x,
                 const float* __restrict__ w,
                 float* __restrict__ out) {
    const int tid = threadIdx.x;
    const int xc  = tid & 15;            // position within 16-wide chunk (fastest)
    const int b   = tid >> 4;            // batch
    const int x0  = blockIdx.x * 16;     // 0,16,32,48
    const int y   = blockIdx.y;          // 0..61
    const int o0  = blockIdx.z * TO;     // 0 or 8

    const int  xpos  = x0 + xc;
    const bool valid = (xpos < OW_);
    const int  xp    = valid ? xpos : (OW_ - 1);   // clamp for loads; store masked

    float acc[TO];
    #pragma unroll
    for (int t = 0; t < TO; ++t) acc[t] = 0.f;

    // x base for (b, c=0, y, xp)
    const float* xb = x + (size_t)b * (CIN * H_ * W_) + (size_t)y * W_ + xp;
    // w base for (o0, c=0, y, xp, k=0); strides: o: CIN*OH*OW*9, c: OH*OW*9
    const size_t WOSTR = (size_t)CIN * OH_ * OW_ * 9;   // 553536
    const size_t WCSTR = (size_t)OH_ * OW_ * 9;         // 34596
    const float* wb = w + (size_t)o0 * WOSTR + ((size_t)y * OW_ + xp) * 9;

    for (int c = 0; c < CIN; ++c) {
        const float* xr = xb + (size_t)c * (H_ * W_);
        const float* wc = wb + (size_t)c * WCSTR;

        float xv[9];
        #pragma unroll
        for (int i = 0; i < 3; ++i)
            #pragma unroll
            for (int j = 0; j < 3; ++j)
                xv[i * 3 + j] = xr[i * W_ + j];

        #pragma unroll
        for (int k = 0; k < 9; ++k) {
            #pragma unroll
            for (int t = 0; t < TO; ++t) {
                acc[t] = fmaf(wc[(size_t)t * WOSTR + k], xv[k], acc[t]);
            }
        }
    }

    if (valid) {
        float* ob = out + (size_t)b * (COUT * OH_ * OW_)
                        + (size_t)o0 * (OH_ * OW_)
                        + (size_t)y * OW_ + xpos;
        #pragma unroll
        for (int t = 0; t < TO; ++t)
            ob[(size_t)t * (OH_ * OW_)] = acc[t];
    }
}

extern "C" void kernel_launch(void* const* d_in, const int* in_sizes, int n_in,
                              void* d_out, int out_size, void* d_ws, size_t ws_size,
                              hipStream_t stream) {
    const float* x = (const float*)d_in[0];
    const float* w = (const float*)d_in[1];
    float* out = (float*)d_out;

    dim3 grid(4, OH_, COUT / TO);   // x-chunks, y rows, o-tiles
    dim3 block(256);
    lc2d_kernel<<<grid, block, 0, stream>>>(x, w, out);
}

// Round 2
// 90.653 us; speedup vs baseline: 1.1826x; 1.1826x over previous
//
#include <hip/hip_runtime.h>

// LocallyConnected2d: out[b,o,y,x] = sum_{c,i,j} x[b,c,y+i,x+j] * w[o,c,y,x,i*3+j]
// B=16, C_IN=16, H=W=64, C_OUT=16, KH=KW=3, OH=OW=62.
//
// Round 2: w staged into LDS via coalesced float2 loads (w's [x][9] run is 288
// contiguous floats per (o,c)); LDS k-rows padded to 12 + mod-3 chunk rotation
// swizzle -> ~2-way conflicts (free). Compute tile 4o x 4b per thread.
// Register prefetch of next-c w hides HBM latency (only ~1 block/CU).

#define CIN   16
#define COUT  16
#define HH    64
#define WW    64
#define OHH   62
#define OWW   62

#define WOSTR (CIN * OHH * OWW * 9)   // 553536 floats: o stride in w
#define WCSTR (OHH * OWW * 9)         // 34596 floats: c stride in w
#define OROW  388                     // per-o LDS stride in dwords (32*12 + 4 pad)

__device__ __forceinline__ int ldsIdx(int o, int xi, int k) {
    int j = k >> 2;                // chunk 0:k0-3, 1:k4-7, 2:k8
    int p = (j + xi) % 3;          // rotate chunks by x -> breaks stride-12 bank pattern
    return o * OROW + xi * 12 + p * 4 + (k & 3);
}

__global__ __launch_bounds__(256, 1)
void lc2d(const float* __restrict__ xg,
          const float* __restrict__ wg,
          float* __restrict__ outg)
{
    __shared__ float Wl[8 * OROW];   // 12.4 KB

    const int tid = threadIdx.x;
    const int y   = blockIdx.x;          // 0..61
    const int xh  = blockIdx.y;          // 0..1  (x half)
    const int oh  = blockIdx.z;          // 0..1  (o half)
    const int x0  = xh * 32;
    const int nx  = xh ? (OWW - 32) : 32;     // 30 or 32 valid positions
    const int M   = nx * 9 / 2;               // float2 per (o,c) run (144 or 135)
    const int tot = 8 * M;

    // compute-role indices: tid = xl + og*32 + bg*64
    const int xl  = tid & 31;
    const int og  = (tid >> 5) & 1;
    const int bg  = tid >> 6;            // wave id -> 4 b's
    const int pos = x0 + xl;
    const bool valid = pos < OWW;
    const int xp  = valid ? pos : (OWW - 1);

    // staging descriptors (c-invariant): flat float2 id -> (o, float-offset in run)
    int st_o[5], st_fo[5];
    bool st_en[5];
    #pragma unroll
    for (int r = 0; r < 5; ++r) {
        int id = tid + 256 * r;
        st_en[r] = id < tot;
        int idc = st_en[r] ? id : 0;
        int o = idc / M;                 // M is block-uniform
        st_o[r]  = o;
        st_fo[r] = 2 * (idc - o * M);
    }

    const float* wbase = wg + (size_t)oh * 8 * WOSTR + (size_t)(y * OWW + x0) * 9;

    // ---- prologue: stage c = 0 ----
    float2 pf[5];
    #pragma unroll
    for (int r = 0; r < 5; ++r)
        if (st_en[r])
            pf[r] = *(const float2*)(wbase + (size_t)st_o[r] * WOSTR + st_fo[r]);
    #pragma unroll
    for (int r = 0; r < 5; ++r) {
        if (st_en[r]) {
            int fo = st_fo[r];
            int xi = fo / 9;
            int k  = fo - xi * 9;
            Wl[ldsIdx(st_o[r], xi, k)] = pf[r].x;
            int xi2 = (k == 8) ? xi + 1 : xi;
            int k2  = (k == 8) ? 0 : k + 1;
            Wl[ldsIdx(st_o[r], xi2, k2)] = pf[r].y;
        }
    }
    __syncthreads();

    float acc[4][4];
    #pragma unroll
    for (int t = 0; t < 4; ++t)
        #pragma unroll
        for (int b = 0; b < 4; ++b) acc[t][b] = 0.f;

    const float* xbb = xg + (size_t)y * WW + xp;

    for (int c = 0; c < CIN; ++c) {
        // prefetch next c's w into registers (lands during compute)
        float2 npf[5];
        if (c + 1 < CIN) {
            #pragma unroll
            for (int r = 0; r < 5; ++r)
                if (st_en[r])
                    npf[r] = *(const float2*)(wbase + (size_t)st_o[r] * WOSTR
                                              + (size_t)(c + 1) * WCSTR + st_fo[r]);
        }

        // x patches for this thread's 4 b's (coalesced: 32 lanes x contiguous dwords)
        float xv[4][9];
        #pragma unroll
        for (int b = 0; b < 4; ++b) {
            const float* xr = xbb + (size_t)(bg * 4 + b) * (CIN * HH * WW)
                                  + (size_t)c * (HH * WW);
            #pragma unroll
            for (int i = 0; i < 3; ++i)
                #pragma unroll
                for (int j = 0; j < 3; ++j)
                    xv[b][i * 3 + j] = xr[i * WW + j];
        }

        // 4 o's x 4 b's x 9 k FMAs; W via 2x b128 + 1x b32 LDS reads per o
        #pragma unroll
        for (int t = 0; t < 4; ++t) {
            const int lo   = og * 4 + t;
            const int base = lo * OROW + xl * 12;
            const int p0   = xl % 3;
            const float4 w0 = *(const float4*)&Wl[base + p0 * 4];                  // k0..3
            const float4 w1 = *(const float4*)&Wl[base + ((p0 + 1) % 3) * 4];      // k4..7
            const float  w8 = Wl[base + ((p0 + 2) % 3) * 4];                       // k8
            #pragma unroll
            for (int b = 0; b < 4; ++b) {
                float s = acc[t][b];
                s = fmaf(w0.x, xv[b][0], s);
                s = fmaf(w0.y, xv[b][1], s);
                s = fmaf(w0.z, xv[b][2], s);
                s = fmaf(w0.w, xv[b][3], s);
                s = fmaf(w1.x, xv[b][4], s);
                s = fmaf(w1.y, xv[b][5], s);
                s = fmaf(w1.z, xv[b][6], s);
                s = fmaf(w1.w, xv[b][7], s);
                s = fmaf(w8,   xv[b][8], s);
                acc[t][b] = s;
            }
        }

        if (c + 1 < CIN) {
            __syncthreads();   // all reads of current buffer done
            #pragma unroll
            for (int r = 0; r < 5; ++r) {
                if (st_en[r]) {
                    int fo = st_fo[r];
                    int xi = fo / 9;
                    int k  = fo - xi * 9;
                    Wl[ldsIdx(st_o[r], xi, k)] = npf[r].x;
                    int xi2 = (k == 8) ? xi + 1 : xi;
                    int k2  = (k == 8) ? 0 : k + 1;
                    Wl[ldsIdx(st_o[r], xi2, k2)] = npf[r].y;
                }
            }
            __syncthreads();   // new tile visible
        }
    }

    if (valid) {
        #pragma unroll
        for (int t = 0; t < 4; ++t) {
            const int o = oh * 8 + og * 4 + t;
            #pragma unroll
            for (int b = 0; b < 4; ++b) {
                const int bb = bg * 4 + b;
                outg[((size_t)(bb * COUT + o) * OHH + y) * OWW + pos] = acc[t][b];
            }
        }
    }
}

extern "C" void kernel_launch(void* const* d_in, const int* in_sizes, int n_in,
                              void* d_out, int out_size, void* d_ws, size_t ws_size,
                              hipStream_t stream) {
    const float* x = (const float*)d_in[0];
    const float* w = (const float*)d_in[1];
    float* out = (float*)d_out;

    dim3 grid(OHH, 2, 2);   // y rows, x halves, o halves
    dim3 block(256);
    lc2d<<<grid, block, 0, stream>>>(x, w, out);
}

// Round 3
// 89.118 us; speedup vs baseline: 1.2030x; 1.0172x over previous
//
#include <hip/hip_runtime.h>

// LocallyConnected2d: out[b,o,y,x] = sum_{c,i,j} x[b,c,y+i,x+j] * w[o,c,y,x,i*3+j]
// B=16, C_IN=16, H=W=64, C_OUT=16, KH=KW=3, OH=OW=62.
//
// Round 3: 512-thread blocks (8 waves -> 2 waves/SIMD for latency overlap),
// double-buffered LDS w-tile -> one __syncthreads per c-iter (was 2),
// thread tile 4o x 2b. w staged via coalesced float2 (contiguous [x][9] run),
// LDS rows padded to 12 + mod-3 chunk rotation -> ~2-way conflicts (free).

#define CIN   16
#define COUT  16
#define HH    64
#define WW    64
#define OHH   62
#define OWW   62

#define WOSTR (CIN * OHH * OWW * 9)   // 553536 floats: o stride in w
#define WCSTR (OHH * OWW * 9)         // 34596 floats: c stride in w
#define OROW  388                     // per-o LDS stride in dwords (32*12 + 4 pad)

__device__ __forceinline__ int ldsIdx(int o, int xi, int k) {
    int j = k >> 2;                // chunk 0:k0-3, 1:k4-7, 2:k8
    int p = (j + xi) % 3;          // rotate chunks by x -> breaks stride-12 bank pattern
    return o * OROW + xi * 12 + p * 4 + (k & 3);
}

__global__ __launch_bounds__(512, 1)
void lc2d(const float* __restrict__ xg,
          const float* __restrict__ wg,
          float* __restrict__ outg)
{
    __shared__ float Wl[2][8 * OROW];   // 2 x 12.4 KB

    const int tid = threadIdx.x;
    const int y   = blockIdx.x;          // 0..61
    const int xh  = blockIdx.y;          // 0..1  (x half)
    const int oh  = blockIdx.z;          // 0..1  (o half)
    const int x0  = xh * 32;
    const int nx  = xh ? (OWW - 32) : 32;     // 30 or 32 valid positions
    const int M   = nx * 9 / 2;               // float2 per (o,c) run (144 or 135)
    const int tot = 8 * M;

    // compute-role indices: tid = xl + og*32 + bg*64
    const int xl  = tid & 31;
    const int og  = (tid >> 5) & 1;      // selects 4-of-8 o
    const int bg  = tid >> 6;            // wave id 0..7 -> 2 b's
    const int pos = x0 + xl;
    const bool valid = pos < OWW;
    const int xp  = valid ? pos : (OWW - 1);

    // staging descriptors (c-invariant): flat float2 id -> (o, float-offset in run)
    int st_o[3], st_fo[3];
    bool st_en[3];
    #pragma unroll
    for (int r = 0; r < 3; ++r) {
        int id = tid + 512 * r;
        st_en[r] = id < tot;
        int idc = st_en[r] ? id : 0;
        int o = idc / M;                 // M is block-uniform
        st_o[r]  = o;
        st_fo[r] = 2 * (idc - o * M);
    }
    // precomputed LDS write slots (c-invariant)
    int wr0[3], wr1[3];
    #pragma unroll
    for (int r = 0; r < 3; ++r) {
        int fo = st_fo[r];
        int xi = fo / 9;
        int k  = fo - xi * 9;
        wr0[r] = ldsIdx(st_o[r], xi, k);
        int xi2 = (k == 8) ? xi + 1 : xi;
        int k2  = (k == 8) ? 0 : k + 1;
        wr1[r] = ldsIdx(st_o[r], xi2, k2);
    }

    const float* wbase = wg + (size_t)oh * 8 * WOSTR + (size_t)(y * OWW + x0) * 9;

    // ---- prologue: stage c = 0 into buffer 0 ----
    {
        float2 pf[3];
        #pragma unroll
        for (int r = 0; r < 3; ++r)
            if (st_en[r])
                pf[r] = *(const float2*)(wbase + (size_t)st_o[r] * WOSTR + st_fo[r]);
        #pragma unroll
        for (int r = 0; r < 3; ++r) {
            if (st_en[r]) {
                Wl[0][wr0[r]] = pf[r].x;
                Wl[0][wr1[r]] = pf[r].y;
            }
        }
    }
    __syncthreads();

    float acc[4][2];
    #pragma unroll
    for (int t = 0; t < 4; ++t) {
        acc[t][0] = 0.f; acc[t][1] = 0.f;
    }

    // x bases for this thread's 2 b's
    const float* xb0 = xg + ((size_t)(bg * 2 + 0) * CIN) * (HH * WW) + (size_t)y * WW + xp;
    const float* xb1 = xg + ((size_t)(bg * 2 + 1) * CIN) * (HH * WW) + (size_t)y * WW + xp;

    // per-thread chunk rotation offsets (xl fixed)
    const int p0 = (xl % 3) * 4;
    const int p1 = ((xl + 1) % 3) * 4;
    const int p2 = ((xl + 2) % 3) * 4;

    for (int c = 0; c < CIN; ++c) {
        const float* cur = Wl[c & 1];
        float*       nxt = Wl[(c + 1) & 1];

        // prefetch next c's w into registers (in flight across the compute phase)
        float2 npf[3];
        if (c + 1 < CIN) {
            #pragma unroll
            for (int r = 0; r < 3; ++r)
                if (st_en[r])
                    npf[r] = *(const float2*)(wbase + (size_t)st_o[r] * WOSTR
                                              + (size_t)(c + 1) * WCSTR + st_fo[r]);
        }

        // x patches for this thread's 2 b's (coalesced 32-lane segments)
        float xv[2][9];
        {
            const float* xr0 = xb0 + (size_t)c * (HH * WW);
            const float* xr1 = xb1 + (size_t)c * (HH * WW);
            #pragma unroll
            for (int i = 0; i < 3; ++i)
                #pragma unroll
                for (int j = 0; j < 3; ++j) {
                    xv[0][i * 3 + j] = xr0[i * WW + j];
                    xv[1][i * 3 + j] = xr1[i * WW + j];
                }
        }

        // 4 o's x 2 b's x 9 k FMAs; W via 2x b128 + 1x b32 LDS reads per o
        #pragma unroll
        for (int t = 0; t < 4; ++t) {
            const int base = (og * 4 + t) * OROW + xl * 12;
            const float4 w0 = *(const float4*)&cur[base + p0];    // k0..3
            const float4 w1 = *(const float4*)&cur[base + p1];    // k4..7
            const float  w8 = cur[base + p2];                     // k8
            #pragma unroll
            for (int b = 0; b < 2; ++b) {
                float s = acc[t][b];
                s = fmaf(w0.x, xv[b][0], s);
                s = fmaf(w0.y, xv[b][1], s);
                s = fmaf(w0.z, xv[b][2], s);
                s = fmaf(w0.w, xv[b][3], s);
                s = fmaf(w1.x, xv[b][4], s);
                s = fmaf(w1.y, xv[b][5], s);
                s = fmaf(w1.z, xv[b][6], s);
                s = fmaf(w1.w, xv[b][7], s);
                s = fmaf(w8,   xv[b][8], s);
                acc[t][b] = s;
            }
        }

        if (c + 1 < CIN) {
            // write prefetched tile to the other buffer; no read hazard:
            // reads of `nxt` finished before the barrier that ended iter c-1
            #pragma unroll
            for (int r = 0; r < 3; ++r) {
                if (st_en[r]) {
                    nxt[wr0[r]] = npf[r].x;
                    nxt[wr1[r]] = npf[r].y;
                }
            }
            __syncthreads();   // one barrier per c-iter
        }
    }

    if (valid) {
        #pragma unroll
        for (int t = 0; t < 4; ++t) {
            const int o = oh * 8 + og * 4 + t;
            #pragma unroll
            for (int b = 0; b < 2; ++b) {
                const int bb = bg * 2 + b;
                outg[((size_t)(bb * COUT + o) * OHH + y) * OWW + pos] = acc[t][b];
            }
        }
    }
}

extern "C" void kernel_launch(void* const* d_in, const int* in_sizes, int n_in,
                              void* d_out, int out_size, void* d_ws, size_t ws_size,
                              hipStream_t stream) {
    const float* x = (const float*)d_in[0];
    const float* w = (const float*)d_in[1];
    float* out = (float*)d_out;

    dim3 grid(OHH, 2, 2);   // y rows, x halves, o halves
    dim3 block(512);
    lc2d<<<grid, block, 0, stream>>>(x, w, out);
}